// Round 9
// baseline (202.023 us; speedup 1.0000x reference)
//
#include <hip/hip_runtime.h>
#include <hip/hip_bf16.h>
#include <cstdint>
#include <cstddef>

// ---------- types ----------
typedef __bf16 bf16x8 __attribute__((ext_vector_type(8)));
typedef float f32x4 __attribute__((ext_vector_type(4)));

__device__ __forceinline__ unsigned short f2bf(float f) {
    unsigned u = __builtin_bit_cast(unsigned, f);
    u += 0x7FFFu + ((u >> 16) & 1u);   // round-to-nearest-even
    return (unsigned short)(u >> 16);
}
// packed f32x2 -> bf16x2 via native HW convert (RTNE)
__device__ __forceinline__ unsigned pk2(float a, float b) {
    typedef __bf16 bf16x2 __attribute__((ext_vector_type(2)));
    bf16x2 h;
    h[0] = (__bf16)a;
    h[1] = (__bf16)b;
    unsigned r;
    __builtin_memcpy(&r, &h, 4);
    return r;
}
__device__ __forceinline__ float fexp2(float x) {
#if __has_builtin(__builtin_amdgcn_exp2f)
    return __builtin_amdgcn_exp2f(x);
#else
    return __expf(x * 0.6931471805599453f);
#endif
}
// async global->LDS, 16B per lane. LDS dest must be uniform-base + lane*16.
__device__ __forceinline__ void gld16(const void* g, void* l) {
    __builtin_amdgcn_global_load_lds((const __attribute__((address_space(1))) void*)g,
                                     (__attribute__((address_space(3))) void*)l, 16, 0, 0);
}

// ---------- 1. fp32 -> bf16 cast ----------
__global__ __launch_bounds__(256) void cast_kernel(const float4* __restrict__ x,
                                                   const float4* __restrict__ w,
                                                   ushort4* __restrict__ xbf,
                                                   ushort4* __restrict__ wbf) {
    int i = blockIdx.x * 256 + threadIdx.x;
    const int NX4 = 4096 * 1024 / 4;
    const int NW4 = 2560 * 1024 / 4;
    float4 v;
    ushort4* o;
    if (i < NX4) { v = x[i]; o = xbf + i; }
    else {
        int j = i - NX4;
        if (j >= NW4) return;
        v = w[j]; o = wbf + j;
    }
    ushort4 r;
    r.x = f2bf(v.x); r.y = f2bf(v.y); r.z = f2bf(v.z); r.w = f2bf(v.w);
    *o = r;
}

// ---------- 2/6. bf16 GEMM: 64x128 tile, BK=64, XOR-swizzled LDS, dbuf ----------
__global__ __launch_bounds__(256) void gemm_bf16(const ushort* __restrict__ A,
                                                 const ushort* __restrict__ B,
                                                 float* __restrict__ C,
                                                 int M, int N, int K) {
    __shared__ __align__(16) ushort LA[2][4096];   //  64 rows x 64 k
    __shared__ __align__(16) ushort LB[2][8192];   // 128 rows x 64 k
    int tid = threadIdx.x;
    int w = tid >> 6, lane = tid & 63;
    int qm = lane & 15, quad = lane >> 4;
    int m0 = blockIdx.x * 64, n0 = blockIdx.y * 128;
    int mw = (w & 1) * 32, nw = (w >> 1) * 64;
    int sw = qm & 7;

    f32x4 acc[2][4];
#pragma unroll
    for (int i = 0; i < 2; i++)
#pragma unroll
        for (int j = 0; j < 4; j++) acc[i][j] = (f32x4){0.f, 0.f, 0.f, 0.f};

    int sa[2], ra[2], ga[2];
#pragma unroll
    for (int u = 0; u < 2; u++) {
        sa[u] = tid + u * 256;
        ra[u] = sa[u] >> 3;
        ga[u] = (sa[u] & 7) ^ (ra[u] & 7);
    }
    int sb[4], rb[4], gb[4];
#pragma unroll
    for (int u = 0; u < 4; u++) {
        sb[u] = tid + u * 256;
        rb[u] = sb[u] >> 3;
        gb[u] = (sb[u] & 7) ^ (rb[u] & 7);
    }

    auto do_stage = [&](int k0, int buf) {
#pragma unroll
        for (int u = 0; u < 2; u++)
            gld16(A + (size_t)(m0 + ra[u]) * K + k0 + ga[u] * 8, &LA[buf][sa[u] * 8]);
#pragma unroll
        for (int u = 0; u < 4; u++)
            gld16(B + (size_t)(n0 + rb[u]) * K + k0 + gb[u] * 8, &LB[buf][sb[u] * 8]);
    };

    do_stage(0, 0);
    int buf = 0;
    for (int k0 = 0; k0 < K; k0 += 64, buf ^= 1) {
        __syncthreads();
        if (k0 + 64 < K) do_stage(k0 + 64, buf ^ 1);
        bf16x8 a[2][2], bb[4][2];
#pragma unroll
        for (int mi = 0; mi < 2; mi++)
#pragma unroll
            for (int h = 0; h < 2; h++)
                a[mi][h] = *(const bf16x8*)&LA[buf][((mw + mi * 16 + qm) * 8 + ((h * 4 + quad) ^ sw)) * 8];
#pragma unroll
        for (int ni = 0; ni < 4; ni++)
#pragma unroll
            for (int h = 0; h < 2; h++)
                bb[ni][h] = *(const bf16x8*)&LB[buf][((nw + ni * 16 + qm) * 8 + ((h * 4 + quad) ^ sw)) * 8];
#pragma unroll
        for (int h = 0; h < 2; h++)
#pragma unroll
            for (int mi = 0; mi < 2; mi++)
#pragma unroll
                for (int ni = 0; ni < 4; ni++)
                    acc[mi][ni] = __builtin_amdgcn_mfma_f32_16x16x32_bf16(a[mi][h], bb[ni][h], acc[mi][ni], 0, 0, 0);
    }
#pragma unroll
    for (int mi = 0; mi < 2; mi++)
#pragma unroll
        for (int ni = 0; ni < 4; ni++) {
            int row = m0 + mw + mi * 16 + quad * 4;
            int col = n0 + nw + ni * 16 + qm;
            float* cp = C + (size_t)row * N + col;
#pragma unroll
            for (int r = 0; r < 4; r++) cp[(size_t)r * N] = acc[mi][ni][r];
        }
}

// ---------- 3. fused RMSNorm + RoPE ----------
__global__ __launch_bounds__(256) void normrope_kernel(const float* __restrict__ qkv,
                                                       const float* __restrict__ qw,
                                                       const float* __restrict__ kw,
                                                       ushort* __restrict__ Q,
                                                       ushort* __restrict__ Kb) {
    int r = blockIdx.x;          // b*2048 + t
    int b = r >> 11;
    int t = r & 2047;
    int tid = threadIdx.x;
    int w = tid >> 6;
    int lane = tid & 63;

    float inv_freq = __expf(-((float)(lane & 62) * (1.0f / 64.0f)) * 9.210340371976184f);
    float sn, cs;
    sincosf((float)t * inv_freq, &sn, &cs);

#pragma unroll
    for (int hg = 0; hg < 5; hg++) {
        int col = hg * 256 + w * 64 + lane;
        float v = qkv[(size_t)r * 1536 + col];
        float ss = v * v;
#pragma unroll
        for (int m = 1; m < 64; m <<= 1) ss += __shfl_xor(ss, m);
        float rinv = rsqrtf(ss * (1.0f / 64.0f) + 1.1920929e-7f);
        float wt = (hg < 4) ? qw[lane] : kw[lane];
        float vn = v * rinv * wt;
        float pr = __shfl_xor(vn, 1);
        float out = (lane & 1) ? fmaf(pr, sn, vn * cs) : fmaf(vn, cs, -pr * sn);
        if (hg < 4) {
            int h = hg * 4 + w;
            Q[((size_t)(b * 16 + h) * 2048 + t) * 64 + lane] = f2bf(out * 0.125f);
        } else {
            Kb[((size_t)(b * 4 + w) * 2048 + t) * 64 + lane] = f2bf(out);
        }
    }
}

// ---------- 4. V transpose with PERMUTED key order ----------
// Within each 32-key block, key kk (= 16t + 4q2 + r) is stored at position
// q2*8 + t*4 + r, matching the MFMA k-permutation of attn's PV step.
__global__ __launch_bounds__(256) void vtrans_kernel(const float* __restrict__ qkv,
                                                     ushort* __restrict__ VT) {
    __shared__ float tile[64][65];
    int bkv = blockIdx.x;
    int t0 = blockIdx.y * 64;
    int b = bkv >> 2;
    int kvh = bkv & 3;
    int tid = threadIdx.x;
    int c = tid & 63;
    int rr = tid >> 6;
#pragma unroll
    for (int p = 0; p < 16; p++) {
        int tl = p * 4 + rr;
        tile[tl][c] = qkv[((size_t)(b * 2048) + t0 + tl) * 1536 + 1280 + kvh * 64 + c];
    }
    __syncthreads();
    int w5 = c & 31;
    int pc = (c & 32) + ((w5 >> 2) & 3) * 8 + (w5 >> 4) * 4 + (w5 & 3);
#pragma unroll
    for (int p = 0; p < 16; p++) {
        int dd = p * 4 + rr;
        VT[((size_t)bkv * 64 + dd) * 2048 + t0 + pc] = f2bf(tile[c][dd]);
    }
}

// ---------- 5. attn v8: balanced CU assignment + K direct from global ----------
// All 1024 blocks are co-resident; CU = f(blk mod 256) under linear and
// XCD-round-robin models. qp chosen so {c, c+256, c+512, c+768} get
// {y, 31-y, (y+8)&31, (23-y)&31}: every CU sums to exactly 66 chunk-units.
// K frags load straight from global (A-operand order is coalesced); only V
// is LDS-staged (dbuf, 16 KB total). P stays in registers (k-permutation).
__global__ __launch_bounds__(256) void attn8_kernel(const ushort* __restrict__ Q,
                                                    const ushort* __restrict__ K,
                                                    const ushort* __restrict__ VT,
                                                    ushort* __restrict__ O) {
    __shared__ __align__(16) ushort VL[2][4096];    // V^T chunk (key-permuted)

    const float LOG2E = 1.4426950408889634f;
    const float C8 = 11.541560327111707f;           // 8 * log2(e)

    int blk = blockIdx.x;
    int rnd = blk >> 8;                // 0..3
    int c = blk & 255;
    int y = c >> 3;
    int qp;
    if (rnd == 0)      qp = y;
    else if (rnd == 1) qp = 31 - y;
    else if (rnd == 2) qp = (y + 8) & 31;
    else               qp = (23 - y) & 31;
    int bh = (rnd << 3) | (c & 7);

    int tid = threadIdx.x;
    int w = tid >> 6, lane = tid & 63;
    int qm = lane & 15, quad = lane >> 4;
    int b = bh >> 4, h = bh & 15;
    int bkv = b * 4 + (h >> 2);

    const ushort* Qbh = Q + (size_t)bh * 2048 * 64;
    const ushort* Kbh = K + (size_t)bkv * 2048 * 64;
    const ushort* Vbh = VT + (size_t)bkv * 64 * 2048;
    int sw = qm & 7;

    int s0 = tid, s1 = tid + 256;
    int r0 = s0 >> 3, g0 = (s0 & 7) ^ (r0 & 7);
    int r1 = s1 >> 3, g1 = (s1 & 7) ^ (r1 & 7);

    auto do_stage = [&](int j0, int buf) {
        gld16(Vbh + (size_t)r0 * 2048 + j0 + g0 * 8, &VL[buf][s0 * 8]);
        gld16(Vbh + (size_t)r1 * 2048 + j0 + g1 * 8, &VL[buf][s1 * 8]);
    };

    int nch = qp + 1;
    int q0 = qp * 64 + w * 16;
    const ushort* qptr = Qbh + (size_t)(q0 + qm) * 64 + quad * 8;
    bf16x8 qb0 = *(const bf16x8*)qptr;
    bf16x8 qb1 = *(const bf16x8*)(qptr + 32);
    f32x4 oacc[4];
    float lacc = 0.f;
#pragma unroll
    for (int i = 0; i < 4; i++) oacc[i] = (f32x4){0.f, 0.f, 0.f, 0.f};

    do_stage(0, 0);
    int buf = 0;
#pragma unroll 1
    for (int i = 0; i < nch; i++, buf ^= 1) {
        int j0 = i * 64;
        __syncthreads();               // staged V buf ready
        if (i + 1 < nch) do_stage(j0 + 64, buf ^ 1);

        // ---- S^T = K Q^T, K frags straight from global ----
        const ushort* kc = Kbh + (size_t)(j0 + qm) * 64 + quad * 8;
        f32x4 st[4];
#pragma unroll
        for (int tj = 0; tj < 4; tj++) st[tj] = (f32x4){0.f, 0.f, 0.f, 0.f};
#pragma unroll
        for (int tj = 0; tj < 4; tj++) {
            bf16x8 kf0 = *(const bf16x8*)(kc + (size_t)tj * 16 * 64);
            bf16x8 kf1 = *(const bf16x8*)(kc + (size_t)tj * 16 * 64 + 32);
            st[tj] = __builtin_amdgcn_mfma_f32_16x16x32_bf16(kf0, qb0, st[tj], 0, 0, 0);
            st[tj] = __builtin_amdgcn_mfma_f32_16x16x32_bf16(kf1, qb1, st[tj], 0, 0, 0);
        }
        // st[tj][r] = S^T[key = j0+16tj+4quad+r][q = q0+qm]
        if (i == nch - 1) {            // diagonal chunk: causal mask
#pragma unroll
            for (int tj = 0; tj < 4; tj++)
#pragma unroll
                for (int r = 0; r < 4; r++) {
                    int key = j0 + tj * 16 + quad * 4 + r;
                    if (key > q0 + qm) st[tj][r] = -1e30f;
                }
        }
        // ---- fixed-max softmax (scores provably in [-8,8]) ----
        float rs = 0.f;
#pragma unroll
        for (int tj = 0; tj < 4; tj++)
#pragma unroll
            for (int r = 0; r < 4; r++) {
                float pv = fexp2(fmaf(st[tj][r], LOG2E, -C8));
                st[tj][r] = pv;
                rs += pv;
            }
        lacc += rs;

        // ---- pack P straight into PV B-operand regs (k-permuted) ----
        unsigned up[4];
        up[0] = pk2(st[0][0], st[0][1]);
        up[1] = pk2(st[0][2], st[0][3]);
        up[2] = pk2(st[1][0], st[1][1]);
        up[3] = pk2(st[1][2], st[1][3]);
        bf16x8 pf0;
        __builtin_memcpy(&pf0, up, 16);
        up[0] = pk2(st[2][0], st[2][1]);
        up[1] = pk2(st[2][2], st[2][3]);
        up[2] = pk2(st[3][0], st[3][1]);
        up[3] = pk2(st[3][2], st[3][3]);
        bf16x8 pf1;
        __builtin_memcpy(&pf1, up, 16);

        // ---- O^T += V^T P^T (V frags from permuted LDS; P from registers) ----
#pragma unroll
        for (int dt = 0; dt < 4; dt++) {
            bf16x8 vf0 = *(const bf16x8*)&VL[buf][((16 * dt + qm) * 8 + (quad ^ sw)) * 8];
            bf16x8 vf1 = *(const bf16x8*)&VL[buf][((16 * dt + qm) * 8 + ((4 + quad) ^ sw)) * 8];
            oacc[dt] = __builtin_amdgcn_mfma_f32_16x16x32_bf16(vf0, pf0, oacc[dt], 0, 0, 0);
            oacc[dt] = __builtin_amdgcn_mfma_f32_16x16x32_bf16(vf1, pf1, oacc[dt], 0, 0, 0);
        }
    }
    // ---- epilogue ----
    float l = lacc;
    l += __shfl_xor(l, 16);
    l += __shfl_xor(l, 32);
    float rinv = 1.0f / l;
    uint2 val;
#pragma unroll
    for (int dt = 0; dt < 4; dt++) {
        val.x = pk2(oacc[dt][0] * rinv, oacc[dt][1] * rinv);
        val.y = pk2(oacc[dt][2] * rinv, oacc[dt][3] * rinv);
        *(uint2*)&O[((size_t)(b * 2048) + q0 + qm) * 1024 + h * 64 + dt * 16 + quad * 4] = val;
    }
}

// ---------- launch ----------
extern "C" void kernel_launch(void* const* d_in, const int* in_sizes, int n_in,
                              void* d_out, int out_size, void* d_ws, size_t ws_size,
                              hipStream_t stream) {
    (void)in_sizes; (void)n_in; (void)out_size; (void)ws_size;
    const float* x    = (const float*)d_in[0];
    const float* qkvo = (const float*)d_in[1];
    const float* qw   = (const float*)d_in[2];
    const float* kw   = (const float*)d_in[3];
    float* out = (float*)d_out;

    char* ws = (char*)d_ws;
    ushort* xbf = (ushort*)(ws + 0);          //  8388608 B
    ushort* wbf = (ushort*)(ws + 8388608);    //  5242880 B
    float*  qkv = (float*)(ws + 13631488);    // 25165824 B
    ushort* Qb  = (ushort*)(ws + 38797312);   //  8388608 B
    ushort* Kb  = (ushort*)(ws + 47185920);   //  2097152 B
    ushort* VT  = (ushort*)(ws + 49283072);   //  2097152 B
    ushort* Ob  = (ushort*)(ws + 51380224);   //  8388608 B

    cast_kernel<<<6656, 256, 0, stream>>>((const float4*)x, (const float4*)qkvo,
                                          (ushort4*)xbf, (ushort4*)wbf);
    gemm_bf16<<<dim3(64, 12), 256, 0, stream>>>(xbf, wbf, qkv, 4096, 1536, 1024);
    normrope_kernel<<<4096, 256, 0, stream>>>(qkv, qw, kw, Qb, Kb);
    vtrans_kernel<<<dim3(8, 32), 256, 0, stream>>>(qkv, VT);
    attn8_kernel<<<1024, 256, 0, stream>>>(Qb, Kb, VT, Ob);
    gemm_bf16<<<dim3(64, 8), 256, 0, stream>>>(Ob, wbf + (size_t)1536 * 1024, out, 4096, 1024, 1024);
}

// Round 10
// 163.464 us; speedup vs baseline: 1.2359x; 1.2359x over previous
//
#include <hip/hip_runtime.h>
#include <hip/hip_bf16.h>
#include <cstdint>
#include <cstddef>

// ---------- types ----------
typedef __bf16 bf16x8 __attribute__((ext_vector_type(8)));
typedef float f32x4 __attribute__((ext_vector_type(4)));

__device__ __forceinline__ unsigned short f2bf(float f) {
    unsigned u = __builtin_bit_cast(unsigned, f);
    u += 0x7FFFu + ((u >> 16) & 1u);   // round-to-nearest-even
    return (unsigned short)(u >> 16);
}
// packed f32x2 -> bf16x2 via native HW convert (RTNE)
__device__ __forceinline__ unsigned pk2(float a, float b) {
    typedef __bf16 bf16x2 __attribute__((ext_vector_type(2)));
    bf16x2 h;
    h[0] = (__bf16)a;
    h[1] = (__bf16)b;
    unsigned r;
    __builtin_memcpy(&r, &h, 4);
    return r;
}
__device__ __forceinline__ float fexp2(float x) {
#if __has_builtin(__builtin_amdgcn_exp2f)
    return __builtin_amdgcn_exp2f(x);
#else
    return __expf(x * 0.6931471805599453f);
#endif
}
// async global->LDS, 16B per lane. LDS dest must be uniform-base + lane*16.
__device__ __forceinline__ void gld16(const void* g, void* l) {
    __builtin_amdgcn_global_load_lds((const __attribute__((address_space(1))) void*)g,
                                     (__attribute__((address_space(3))) void*)l, 16, 0, 0);
}

// ---------- 1. fp32 -> bf16 cast ----------
__global__ __launch_bounds__(256) void cast_kernel(const float4* __restrict__ x,
                                                   const float4* __restrict__ w,
                                                   ushort4* __restrict__ xbf,
                                                   ushort4* __restrict__ wbf) {
    int i = blockIdx.x * 256 + threadIdx.x;
    const int NX4 = 4096 * 1024 / 4;
    const int NW4 = 2560 * 1024 / 4;
    float4 v;
    ushort4* o;
    if (i < NX4) { v = x[i]; o = xbf + i; }
    else {
        int j = i - NX4;
        if (j >= NW4) return;
        v = w[j]; o = wbf + j;
    }
    ushort4 r;
    r.x = f2bf(v.x); r.y = f2bf(v.y); r.z = f2bf(v.z); r.w = f2bf(v.w);
    *o = r;
}

// ---------- 2/6. bf16 GEMM: 64x128 tile, BK=64, XOR-swizzled LDS, dbuf ----------
__global__ __launch_bounds__(256) void gemm_bf16(const ushort* __restrict__ A,
                                                 const ushort* __restrict__ B,
                                                 float* __restrict__ C,
                                                 int M, int N, int K) {
    __shared__ __align__(16) ushort LA[2][4096];   //  64 rows x 64 k
    __shared__ __align__(16) ushort LB[2][8192];   // 128 rows x 64 k
    int tid = threadIdx.x;
    int w = tid >> 6, lane = tid & 63;
    int qm = lane & 15, quad = lane >> 4;
    int m0 = blockIdx.x * 64, n0 = blockIdx.y * 128;
    int mw = (w & 1) * 32, nw = (w >> 1) * 64;
    int sw = qm & 7;

    f32x4 acc[2][4];
#pragma unroll
    for (int i = 0; i < 2; i++)
#pragma unroll
        for (int j = 0; j < 4; j++) acc[i][j] = (f32x4){0.f, 0.f, 0.f, 0.f};

    int sa[2], ra[2], ga[2];
#pragma unroll
    for (int u = 0; u < 2; u++) {
        sa[u] = tid + u * 256;
        ra[u] = sa[u] >> 3;
        ga[u] = (sa[u] & 7) ^ (ra[u] & 7);
    }
    int sb[4], rb[4], gb[4];
#pragma unroll
    for (int u = 0; u < 4; u++) {
        sb[u] = tid + u * 256;
        rb[u] = sb[u] >> 3;
        gb[u] = (sb[u] & 7) ^ (rb[u] & 7);
    }

    auto do_stage = [&](int k0, int buf) {
#pragma unroll
        for (int u = 0; u < 2; u++)
            gld16(A + (size_t)(m0 + ra[u]) * K + k0 + ga[u] * 8, &LA[buf][sa[u] * 8]);
#pragma unroll
        for (int u = 0; u < 4; u++)
            gld16(B + (size_t)(n0 + rb[u]) * K + k0 + gb[u] * 8, &LB[buf][sb[u] * 8]);
    };

    do_stage(0, 0);
    int buf = 0;
    for (int k0 = 0; k0 < K; k0 += 64, buf ^= 1) {
        __syncthreads();
        if (k0 + 64 < K) do_stage(k0 + 64, buf ^ 1);
        bf16x8 a[2][2], bb[4][2];
#pragma unroll
        for (int mi = 0; mi < 2; mi++)
#pragma unroll
            for (int h = 0; h < 2; h++)
                a[mi][h] = *(const bf16x8*)&LA[buf][((mw + mi * 16 + qm) * 8 + ((h * 4 + quad) ^ sw)) * 8];
#pragma unroll
        for (int ni = 0; ni < 4; ni++)
#pragma unroll
            for (int h = 0; h < 2; h++)
                bb[ni][h] = *(const bf16x8*)&LB[buf][((nw + ni * 16 + qm) * 8 + ((h * 4 + quad) ^ sw)) * 8];
#pragma unroll
        for (int h = 0; h < 2; h++)
#pragma unroll
            for (int mi = 0; mi < 2; mi++)
#pragma unroll
                for (int ni = 0; ni < 4; ni++)
                    acc[mi][ni] = __builtin_amdgcn_mfma_f32_16x16x32_bf16(a[mi][h], bb[ni][h], acc[mi][ni], 0, 0, 0);
    }
#pragma unroll
    for (int mi = 0; mi < 2; mi++)
#pragma unroll
        for (int ni = 0; ni < 4; ni++) {
            int row = m0 + mw + mi * 16 + quad * 4;
            int col = n0 + nw + ni * 16 + qm;
            float* cp = C + (size_t)row * N + col;
#pragma unroll
            for (int r = 0; r < 4; r++) cp[(size_t)r * N] = acc[mi][ni][r];
        }
}

// ---------- 3. fused RMSNorm + RoPE ----------
__global__ __launch_bounds__(256) void normrope_kernel(const float* __restrict__ qkv,
                                                       const float* __restrict__ qw,
                                                       const float* __restrict__ kw,
                                                       ushort* __restrict__ Q,
                                                       ushort* __restrict__ Kb) {
    int r = blockIdx.x;          // b*2048 + t
    int b = r >> 11;
    int t = r & 2047;
    int tid = threadIdx.x;
    int w = tid >> 6;
    int lane = tid & 63;

    float inv_freq = __expf(-((float)(lane & 62) * (1.0f / 64.0f)) * 9.210340371976184f);
    float sn, cs;
    sincosf((float)t * inv_freq, &sn, &cs);

#pragma unroll
    for (int hg = 0; hg < 5; hg++) {
        int col = hg * 256 + w * 64 + lane;
        float v = qkv[(size_t)r * 1536 + col];
        float ss = v * v;
#pragma unroll
        for (int m = 1; m < 64; m <<= 1) ss += __shfl_xor(ss, m);
        float rinv = rsqrtf(ss * (1.0f / 64.0f) + 1.1920929e-7f);
        float wt = (hg < 4) ? qw[lane] : kw[lane];
        float vn = v * rinv * wt;
        float pr = __shfl_xor(vn, 1);
        float out = (lane & 1) ? fmaf(pr, sn, vn * cs) : fmaf(vn, cs, -pr * sn);
        if (hg < 4) {
            int h = hg * 4 + w;
            Q[((size_t)(b * 16 + h) * 2048 + t) * 64 + lane] = f2bf(out * 0.125f);
        } else {
            Kb[((size_t)(b * 4 + w) * 2048 + t) * 64 + lane] = f2bf(out);
        }
    }
}

// ---------- 4. V transpose with PERMUTED key order ----------
// Within each 32-key block, key kk (= 16t + 4q2 + r) is stored at position
// q2*8 + t*4 + r, matching the MFMA k-permutation of attn's PV step.
__global__ __launch_bounds__(256) void vtrans_kernel(const float* __restrict__ qkv,
                                                     ushort* __restrict__ VT) {
    __shared__ float tile[64][65];
    int bkv = blockIdx.x;
    int t0 = blockIdx.y * 64;
    int b = bkv >> 2;
    int kvh = bkv & 3;
    int tid = threadIdx.x;
    int c = tid & 63;
    int rr = tid >> 6;
#pragma unroll
    for (int p = 0; p < 16; p++) {
        int tl = p * 4 + rr;
        tile[tl][c] = qkv[((size_t)(b * 2048) + t0 + tl) * 1536 + 1280 + kvh * 64 + c];
    }
    __syncthreads();
    int w5 = c & 31;
    int pc = (c & 32) + ((w5 >> 2) & 3) * 8 + (w5 >> 4) * 4 + (w5 & 3);
#pragma unroll
    for (int p = 0; p < 16; p++) {
        int dd = p * 4 + rr;
        VT[((size_t)bkv * 64 + dd) * 2048 + t0 + pc] = f2bf(tile[c][dd]);
    }
}

// ---------- 5. attn v9: attn7 structure (K+V LDS-staged dbuf, register P) ----------
// + balanced CU assignment: blocks {c, c+256, c+512, c+768} (same CU under
// blk-mod-256 mapping) get qp {y, 31-y, (y+8)&31, (23-y)&31} -> every CU sums
// to exactly 66 chunk-units; bh = (rnd<<3)|(c&7) covers each (qp,bh) once.
__global__ __launch_bounds__(256) void attn9_kernel(const ushort* __restrict__ Q,
                                                    const ushort* __restrict__ K,
                                                    const ushort* __restrict__ VT,
                                                    ushort* __restrict__ O) {
    __shared__ __align__(16) ushort KT[2][4096];    // K chunk: 64 keys x 64 d
    __shared__ __align__(16) ushort VL[2][4096];    // V^T chunk (key-permuted)

    const float LOG2E = 1.4426950408889634f;
    const float C8 = 11.541560327111707f;           // 8 * log2(e)

    int blk = blockIdx.x;
    int rnd = blk >> 8;                // 0..3
    int c = blk & 255;
    int y = c >> 3;
    int qp;
    if (rnd == 0)      qp = y;
    else if (rnd == 1) qp = 31 - y;
    else if (rnd == 2) qp = (y + 8) & 31;
    else               qp = (23 - y) & 31;
    int bh = (rnd << 3) | (c & 7);

    int tid = threadIdx.x;
    int w = tid >> 6, lane = tid & 63;
    int qm = lane & 15, quad = lane >> 4;
    int b = bh >> 4, h = bh & 15;
    int bkv = b * 4 + (h >> 2);

    const ushort* Qbh = Q + (size_t)bh * 2048 * 64;
    const ushort* Kbh = K + (size_t)bkv * 2048 * 64;
    const ushort* Vbh = VT + (size_t)bkv * 64 * 2048;
    int sw = qm & 7;

    int s0 = tid, s1 = tid + 256;
    int r0 = s0 >> 3, g0 = (s0 & 7) ^ (r0 & 7);
    int r1 = s1 >> 3, g1 = (s1 & 7) ^ (r1 & 7);

    auto do_stage = [&](int j0, int buf) {
        gld16(Kbh + (size_t)(j0 + r0) * 64 + g0 * 8, &KT[buf][s0 * 8]);
        gld16(Kbh + (size_t)(j0 + r1) * 64 + g1 * 8, &KT[buf][s1 * 8]);
        gld16(Vbh + (size_t)r0 * 2048 + j0 + g0 * 8, &VL[buf][s0 * 8]);
        gld16(Vbh + (size_t)r1 * 2048 + j0 + g1 * 8, &VL[buf][s1 * 8]);
    };

    int nch = qp + 1;
    int q0 = qp * 64 + w * 16;
    const ushort* qptr = Qbh + (size_t)(q0 + qm) * 64 + quad * 8;
    bf16x8 qb0 = *(const bf16x8*)qptr;
    bf16x8 qb1 = *(const bf16x8*)(qptr + 32);
    f32x4 oacc[4];
    float lacc = 0.f;
#pragma unroll
    for (int i = 0; i < 4; i++) oacc[i] = (f32x4){0.f, 0.f, 0.f, 0.f};

    do_stage(0, 0);
    int buf = 0;
#pragma unroll 1
    for (int i = 0; i < nch; i++, buf ^= 1) {
        int j0 = i * 64;
        __syncthreads();               // staged buf ready
        if (i + 1 < nch) do_stage(j0 + 64, buf ^ 1);

        // ---- S^T = K Q^T from LDS ----
        f32x4 st[4];
#pragma unroll
        for (int tj = 0; tj < 4; tj++) st[tj] = (f32x4){0.f, 0.f, 0.f, 0.f};
#pragma unroll
        for (int tj = 0; tj < 4; tj++) {
            bf16x8 kf0 = *(const bf16x8*)&KT[buf][((16 * tj + qm) * 8 + (quad ^ sw)) * 8];
            bf16x8 kf1 = *(const bf16x8*)&KT[buf][((16 * tj + qm) * 8 + ((4 + quad) ^ sw)) * 8];
            st[tj] = __builtin_amdgcn_mfma_f32_16x16x32_bf16(kf0, qb0, st[tj], 0, 0, 0);
            st[tj] = __builtin_amdgcn_mfma_f32_16x16x32_bf16(kf1, qb1, st[tj], 0, 0, 0);
        }
        // st[tj][r] = S^T[key = j0+16tj+4quad+r][q = q0+qm]
        if (i == nch - 1) {            // diagonal chunk: causal mask
#pragma unroll
            for (int tj = 0; tj < 4; tj++)
#pragma unroll
                for (int r = 0; r < 4; r++) {
                    int key = j0 + tj * 16 + quad * 4 + r;
                    if (key > q0 + qm) st[tj][r] = -1e30f;
                }
        }
        // ---- fixed-max softmax (scores provably in [-8,8]) ----
        float rs = 0.f;
#pragma unroll
        for (int tj = 0; tj < 4; tj++)
#pragma unroll
            for (int r = 0; r < 4; r++) {
                float pv = fexp2(fmaf(st[tj][r], LOG2E, -C8));
                st[tj][r] = pv;
                rs += pv;
            }
        lacc += rs;

        // ---- pack P straight into PV B-operand regs (k-permuted) ----
        unsigned up[4];
        up[0] = pk2(st[0][0], st[0][1]);
        up[1] = pk2(st[0][2], st[0][3]);
        up[2] = pk2(st[1][0], st[1][1]);
        up[3] = pk2(st[1][2], st[1][3]);
        bf16x8 pf0;
        __builtin_memcpy(&pf0, up, 16);
        up[0] = pk2(st[2][0], st[2][1]);
        up[1] = pk2(st[2][2], st[2][3]);
        up[2] = pk2(st[3][0], st[3][1]);
        up[3] = pk2(st[3][2], st[3][3]);
        bf16x8 pf1;
        __builtin_memcpy(&pf1, up, 16);

        // ---- O^T += V^T P^T (V frags from permuted LDS; P from registers) ----
#pragma unroll
        for (int dt = 0; dt < 4; dt++) {
            bf16x8 vf0 = *(const bf16x8*)&VL[buf][((16 * dt + qm) * 8 + (quad ^ sw)) * 8];
            bf16x8 vf1 = *(const bf16x8*)&VL[buf][((16 * dt + qm) * 8 + ((4 + quad) ^ sw)) * 8];
            oacc[dt] = __builtin_amdgcn_mfma_f32_16x16x32_bf16(vf0, pf0, oacc[dt], 0, 0, 0);
            oacc[dt] = __builtin_amdgcn_mfma_f32_16x16x32_bf16(vf1, pf1, oacc[dt], 0, 0, 0);
        }
    }
    // ---- epilogue ----
    float l = lacc;
    l += __shfl_xor(l, 16);
    l += __shfl_xor(l, 32);
    float rinv = 1.0f / l;
    uint2 val;
#pragma unroll
    for (int dt = 0; dt < 4; dt++) {
        val.x = pk2(oacc[dt][0] * rinv, oacc[dt][1] * rinv);
        val.y = pk2(oacc[dt][2] * rinv, oacc[dt][3] * rinv);
        *(uint2*)&O[((size_t)(b * 2048) + q0 + qm) * 1024 + h * 64 + dt * 16 + quad * 4] = val;
    }
}

// ---------- launch ----------
extern "C" void kernel_launch(void* const* d_in, const int* in_sizes, int n_in,
                              void* d_out, int out_size, void* d_ws, size_t ws_size,
                              hipStream_t stream) {
    (void)in_sizes; (void)n_in; (void)out_size; (void)ws_size;
    const float* x    = (const float*)d_in[0];
    const float* qkvo = (const float*)d_in[1];
    const float* qw   = (const float*)d_in[2];
    const float* kw   = (const float*)d_in[3];
    float* out = (float*)d_out;

    char* ws = (char*)d_ws;
    ushort* xbf = (ushort*)(ws + 0);          //  8388608 B
    ushort* wbf = (ushort*)(ws + 8388608);    //  5242880 B
    float*  qkv = (float*)(ws + 13631488);    // 25165824 B
    ushort* Qb  = (ushort*)(ws + 38797312);   //  8388608 B
    ushort* Kb  = (ushort*)(ws + 47185920);   //  2097152 B
    ushort* VT  = (ushort*)(ws + 49283072);   //  2097152 B
    ushort* Ob  = (ushort*)(ws + 51380224);   //  8388608 B

    cast_kernel<<<6656, 256, 0, stream>>>((const float4*)x, (const float4*)qkvo,
                                          (ushort4*)xbf, (ushort4*)wbf);
    gemm_bf16<<<dim3(64, 12), 256, 0, stream>>>(xbf, wbf, qkv, 4096, 1536, 1024);
    normrope_kernel<<<4096, 256, 0, stream>>>(qkv, qw, kw, Qb, Kb);
    vtrans_kernel<<<dim3(8, 32), 256, 0, stream>>>(qkv, VT);
    attn9_kernel<<<1024, 256, 0, stream>>>(Qb, Kb, VT, Ob);
    gemm_bf16<<<dim3(64, 8), 256, 0, stream>>>(Ob, wbf + (size_t)1536 * 1024, out, 4096, 1024, 1024);
}

// Round 11
// 161.390 us; speedup vs baseline: 1.2518x; 1.0128x over previous
//
#include <hip/hip_runtime.h>
#include <hip/hip_bf16.h>
#include <cstdint>
#include <cstddef>

// ---------- types ----------
typedef __bf16 bf16x8 __attribute__((ext_vector_type(8)));
typedef float f32x4 __attribute__((ext_vector_type(4)));

__device__ __forceinline__ unsigned short f2bf(float f) {
    unsigned u = __builtin_bit_cast(unsigned, f);
    u += 0x7FFFu + ((u >> 16) & 1u);   // round-to-nearest-even
    return (unsigned short)(u >> 16);
}
// packed f32x2 -> bf16x2 via native HW convert (RTNE)
__device__ __forceinline__ unsigned pk2(float a, float b) {
    typedef __bf16 bf16x2 __attribute__((ext_vector_type(2)));
    bf16x2 h;
    h[0] = (__bf16)a;
    h[1] = (__bf16)b;
    unsigned r;
    __builtin_memcpy(&r, &h, 4);
    return r;
}
__device__ __forceinline__ float fexp2(float x) {
#if __has_builtin(__builtin_amdgcn_exp2f)
    return __builtin_amdgcn_exp2f(x);
#else
    return __expf(x * 0.6931471805599453f);
#endif
}
// async global->LDS, 16B per lane. LDS dest must be uniform-base + lane*16.
__device__ __forceinline__ void gld16(const void* g, void* l) {
    __builtin_amdgcn_global_load_lds((const __attribute__((address_space(1))) void*)g,
                                     (__attribute__((address_space(3))) void*)l, 16, 0, 0);
}

// ---------- 1. fp32 -> bf16 cast ----------
__global__ __launch_bounds__(256) void cast_kernel(const float4* __restrict__ x,
                                                   const float4* __restrict__ w,
                                                   ushort4* __restrict__ xbf,
                                                   ushort4* __restrict__ wbf) {
    int i = blockIdx.x * 256 + threadIdx.x;
    const int NX4 = 4096 * 1024 / 4;
    const int NW4 = 2560 * 1024 / 4;
    float4 v;
    ushort4* o;
    if (i < NX4) { v = x[i]; o = xbf + i; }
    else {
        int j = i - NX4;
        if (j >= NW4) return;
        v = w[j]; o = wbf + j;
    }
    ushort4 r;
    r.x = f2bf(v.x); r.y = f2bf(v.y); r.z = f2bf(v.z); r.w = f2bf(v.w);
    *o = r;
}

// ---------- 2/6. bf16 GEMM: 64x128 tile, BK=64, XOR-swizzled LDS, dbuf ----------
__global__ __launch_bounds__(256) void gemm_bf16(const ushort* __restrict__ A,
                                                 const ushort* __restrict__ B,
                                                 float* __restrict__ C,
                                                 int M, int N, int K) {
    __shared__ __align__(16) ushort LA[2][4096];   //  64 rows x 64 k
    __shared__ __align__(16) ushort LB[2][8192];   // 128 rows x 64 k
    int tid = threadIdx.x;
    int w = tid >> 6, lane = tid & 63;
    int qm = lane & 15, quad = lane >> 4;
    int m0 = blockIdx.x * 64, n0 = blockIdx.y * 128;
    int mw = (w & 1) * 32, nw = (w >> 1) * 64;
    int sw = qm & 7;

    f32x4 acc[2][4];
#pragma unroll
    for (int i = 0; i < 2; i++)
#pragma unroll
        for (int j = 0; j < 4; j++) acc[i][j] = (f32x4){0.f, 0.f, 0.f, 0.f};

    int sa[2], ra[2], ga[2];
#pragma unroll
    for (int u = 0; u < 2; u++) {
        sa[u] = tid + u * 256;
        ra[u] = sa[u] >> 3;
        ga[u] = (sa[u] & 7) ^ (ra[u] & 7);
    }
    int sb[4], rb[4], gb[4];
#pragma unroll
    for (int u = 0; u < 4; u++) {
        sb[u] = tid + u * 256;
        rb[u] = sb[u] >> 3;
        gb[u] = (sb[u] & 7) ^ (rb[u] & 7);
    }

    auto do_stage = [&](int k0, int buf) {
#pragma unroll
        for (int u = 0; u < 2; u++)
            gld16(A + (size_t)(m0 + ra[u]) * K + k0 + ga[u] * 8, &LA[buf][sa[u] * 8]);
#pragma unroll
        for (int u = 0; u < 4; u++)
            gld16(B + (size_t)(n0 + rb[u]) * K + k0 + gb[u] * 8, &LB[buf][sb[u] * 8]);
    };

    do_stage(0, 0);
    int buf = 0;
    for (int k0 = 0; k0 < K; k0 += 64, buf ^= 1) {
        __syncthreads();
        if (k0 + 64 < K) do_stage(k0 + 64, buf ^ 1);
        bf16x8 a[2][2], bb[4][2];
#pragma unroll
        for (int mi = 0; mi < 2; mi++)
#pragma unroll
            for (int h = 0; h < 2; h++)
                a[mi][h] = *(const bf16x8*)&LA[buf][((mw + mi * 16 + qm) * 8 + ((h * 4 + quad) ^ sw)) * 8];
#pragma unroll
        for (int ni = 0; ni < 4; ni++)
#pragma unroll
            for (int h = 0; h < 2; h++)
                bb[ni][h] = *(const bf16x8*)&LB[buf][((nw + ni * 16 + qm) * 8 + ((h * 4 + quad) ^ sw)) * 8];
#pragma unroll
        for (int h = 0; h < 2; h++)
#pragma unroll
            for (int mi = 0; mi < 2; mi++)
#pragma unroll
                for (int ni = 0; ni < 4; ni++)
                    acc[mi][ni] = __builtin_amdgcn_mfma_f32_16x16x32_bf16(a[mi][h], bb[ni][h], acc[mi][ni], 0, 0, 0);
    }
#pragma unroll
    for (int mi = 0; mi < 2; mi++)
#pragma unroll
        for (int ni = 0; ni < 4; ni++) {
            int row = m0 + mw + mi * 16 + quad * 4;
            int col = n0 + nw + ni * 16 + qm;
            float* cp = C + (size_t)row * N + col;
#pragma unroll
            for (int r = 0; r < 4; r++) cp[(size_t)r * N] = acc[mi][ni][r];
        }
}

// ---------- 3. fused RMSNorm + RoPE ----------
__global__ __launch_bounds__(256) void normrope_kernel(const float* __restrict__ qkv,
                                                       const float* __restrict__ qw,
                                                       const float* __restrict__ kw,
                                                       ushort* __restrict__ Q,
                                                       ushort* __restrict__ Kb) {
    int r = blockIdx.x;          // b*2048 + t
    int b = r >> 11;
    int t = r & 2047;
    int tid = threadIdx.x;
    int w = tid >> 6;
    int lane = tid & 63;

    float inv_freq = __expf(-((float)(lane & 62) * (1.0f / 64.0f)) * 9.210340371976184f);
    float sn, cs;
    sincosf((float)t * inv_freq, &sn, &cs);

#pragma unroll
    for (int hg = 0; hg < 5; hg++) {
        int col = hg * 256 + w * 64 + lane;
        float v = qkv[(size_t)r * 1536 + col];
        float ss = v * v;
#pragma unroll
        for (int m = 1; m < 64; m <<= 1) ss += __shfl_xor(ss, m);
        float rinv = rsqrtf(ss * (1.0f / 64.0f) + 1.1920929e-7f);
        float wt = (hg < 4) ? qw[lane] : kw[lane];
        float vn = v * rinv * wt;
        float pr = __shfl_xor(vn, 1);
        float out = (lane & 1) ? fmaf(pr, sn, vn * cs) : fmaf(vn, cs, -pr * sn);
        if (hg < 4) {
            int h = hg * 4 + w;
            Q[((size_t)(b * 16 + h) * 2048 + t) * 64 + lane] = f2bf(out * 0.125f);
        } else {
            Kb[((size_t)(b * 4 + w) * 2048 + t) * 64 + lane] = f2bf(out);
        }
    }
}

// ---------- 4. V transpose with PERMUTED key order ----------
// Within each 32-key block, key kk (= 16t + 4q2 + r) is stored at position
// q2*8 + t*4 + r, matching the MFMA k-permutation of attn's PV step.
__global__ __launch_bounds__(256) void vtrans_kernel(const float* __restrict__ qkv,
                                                     ushort* __restrict__ VT) {
    __shared__ float tile[64][65];
    int bkv = blockIdx.x;
    int t0 = blockIdx.y * 64;
    int b = bkv >> 2;
    int kvh = bkv & 3;
    int tid = threadIdx.x;
    int c = tid & 63;
    int rr = tid >> 6;
#pragma unroll
    for (int p = 0; p < 16; p++) {
        int tl = p * 4 + rr;
        tile[tl][c] = qkv[((size_t)(b * 2048) + t0 + tl) * 1536 + 1280 + kvh * 64 + c];
    }
    __syncthreads();
    int w5 = c & 31;
    int pc = (c & 32) + ((w5 >> 2) & 3) * 8 + (w5 >> 4) * 4 + (w5 & 3);
#pragma unroll
    for (int p = 0; p < 16; p++) {
        int dd = p * 4 + rr;
        VT[((size_t)bkv * 64 + dd) * 2048 + t0 + pc] = f2bf(tile[c][dd]);
    }
}

// ---------- 5. attn v10: 3-stage pipeline, raw s_barrier + vmcnt(4) ----------
// Block = tile pair {p, 31-p}: all blocks exactly 33 chunks (no tail).
// Prefetch distance 2 into 3 LDS stage buffers; the barrier does NOT drain
// the in-flight next stage (explicit s_waitcnt vmcnt(4), raw s_barrier).
// Q frags for both tiles preloaded + vmcnt(0)-drained so the vmcnt stream
// in the loop contains only the 4 gld16 per stage (+ benign O stores).
__global__ __launch_bounds__(256) void attn10_kernel(const ushort* __restrict__ Q,
                                                     const ushort* __restrict__ K,
                                                     const ushort* __restrict__ VT,
                                                     ushort* __restrict__ O) {
    __shared__ __align__(16) ushort KT[3][4096];    // K stage: 64 keys x 64 d
    __shared__ __align__(16) ushort VL[3][4096];    // V^T stage (key-permuted)

    const float LOG2E = 1.4426950408889634f;
    const float C8 = 11.541560327111707f;           // 8 * log2(e)

    int blk = blockIdx.x;
    int bh = blk >> 4;                 // 0..31
    int p  = blk & 15;                 // pair index: tiles p and 31-p
    int tid = threadIdx.x;
    int w = tid >> 6, lane = tid & 63;
    int qm = lane & 15, quad = lane >> 4;
    int b = bh >> 4, h = bh & 15;
    int bkv = b * 4 + (h >> 2);

    const ushort* Qbh = Q + (size_t)bh * 2048 * 64;
    const ushort* Kbh = K + (size_t)bkv * 2048 * 64;
    const ushort* Vbh = VT + (size_t)bkv * 64 * 2048;
    int sw = qm & 7;

    int s0 = tid, s1 = tid + 256;
    int r0 = s0 >> 3, g0 = (s0 & 7) ^ (r0 & 7);
    int r1 = s1 >> 3, g1 = (s1 & 7) ^ (r1 & 7);

    int nchA = p + 1;                  // tile A = q-block p; tile B = 31-p
    int q0A = p * 64 + w * 16;
    int q0B = (31 - p) * 64 + w * 16;

    auto do_stage = [&](int si, int stg) {
        int j0 = (si < nchA ? si : si - nchA) * 64;
        gld16(Kbh + (size_t)(j0 + r0) * 64 + g0 * 8, &KT[stg][s0 * 8]);
        gld16(Kbh + (size_t)(j0 + r1) * 64 + g1 * 8, &KT[stg][s1 * 8]);
        gld16(Vbh + (size_t)r0 * 2048 + j0 + g0 * 8, &VL[stg][s0 * 8]);
        gld16(Vbh + (size_t)r1 * 2048 + j0 + g1 * 8, &VL[stg][s1 * 8]);
    };

    // ---- preload BOTH tiles' Q frags, then drain vmcnt so the loop's
    //      vmcnt stream is pure stage traffic ----
    const ushort* qpA = Qbh + (size_t)(q0A + qm) * 64 + quad * 8;
    const ushort* qpB = Qbh + (size_t)(q0B + qm) * 64 + quad * 8;
    bf16x8 qbA0 = *(const bf16x8*)qpA;
    bf16x8 qbA1 = *(const bf16x8*)(qpA + 32);
    bf16x8 qbB0 = *(const bf16x8*)qpB;
    bf16x8 qbB1 = *(const bf16x8*)(qpB + 32);
    asm volatile("s_waitcnt vmcnt(0)" ::: "memory");

    bf16x8 qb0 = qbA0, qb1 = qbA1;
    int q0 = q0A;
    f32x4 oacc[4];
    float lacc = 0.f;
#pragma unroll
    for (int i = 0; i < 4; i++) oacc[i] = (f32x4){0.f, 0.f, 0.f, 0.f};

    auto writeO = [&](int q0v) {
        float l = lacc;
        l += __shfl_xor(l, 16);
        l += __shfl_xor(l, 32);
        float rinv = 1.0f / l;
        uint2 val;
#pragma unroll
        for (int dt = 0; dt < 4; dt++) {
            val.x = pk2(oacc[dt][0] * rinv, oacc[dt][1] * rinv);
            val.y = pk2(oacc[dt][2] * rinv, oacc[dt][3] * rinv);
            *(uint2*)&O[((size_t)(b * 2048) + q0v + qm) * 1024 + h * 64 + dt * 16 + quad * 4] = val;
        }
    };

    do_stage(0, 0);
    do_stage(1, 1);
    int stg = 0;
#pragma unroll 1
    for (int i = 0; i < 33; i++) {
        if (i == nchA) {               // tile switch: flush A, start B
            writeO(q0A);
            qb0 = qbB0; qb1 = qbB1;
            q0 = q0B;
            lacc = 0.f;
#pragma unroll
            for (int ii = 0; ii < 4; ii++) oacc[ii] = (f32x4){0.f, 0.f, 0.f, 0.f};
        }

        // wait only for the OLDEST stage (stage i); stage i+1 stays in flight
        if (i < 32) {
            asm volatile("s_waitcnt vmcnt(4)" ::: "memory");
        } else {
            asm volatile("s_waitcnt vmcnt(0)" ::: "memory");
        }
        asm volatile("s_barrier" ::: "memory");
        if (i <= 30) {
            int stg2 = stg + 2;
            if (stg2 >= 3) stg2 -= 3;
            do_stage(i + 2, stg2);
        }

        int c = (i < nchA) ? i : i - nchA;
        int j0 = c * 64;
        bool diag = (i == nchA - 1) || (i == 32);

        // ---- S^T = K Q^T from LDS stage ----
        f32x4 st[4];
#pragma unroll
        for (int tj = 0; tj < 4; tj++) st[tj] = (f32x4){0.f, 0.f, 0.f, 0.f};
#pragma unroll
        for (int tj = 0; tj < 4; tj++) {
            bf16x8 kf0 = *(const bf16x8*)&KT[stg][((16 * tj + qm) * 8 + (quad ^ sw)) * 8];
            bf16x8 kf1 = *(const bf16x8*)&KT[stg][((16 * tj + qm) * 8 + ((4 + quad) ^ sw)) * 8];
            st[tj] = __builtin_amdgcn_mfma_f32_16x16x32_bf16(kf0, qb0, st[tj], 0, 0, 0);
            st[tj] = __builtin_amdgcn_mfma_f32_16x16x32_bf16(kf1, qb1, st[tj], 0, 0, 0);
        }
        // st[tj][r] = S^T[key = j0+16tj+4quad+r][q = q0+qm]
        if (diag) {                    // causal mask on the diagonal chunk
#pragma unroll
            for (int tj = 0; tj < 4; tj++)
#pragma unroll
                for (int r = 0; r < 4; r++) {
                    int key = j0 + tj * 16 + quad * 4 + r;
                    if (key > q0 + qm) st[tj][r] = -1e30f;
                }
        }
        // ---- fixed-max softmax (scores provably in [-8,8]) ----
        float rs = 0.f;
#pragma unroll
        for (int tj = 0; tj < 4; tj++)
#pragma unroll
            for (int r = 0; r < 4; r++) {
                float pv = fexp2(fmaf(st[tj][r], LOG2E, -C8));
                st[tj][r] = pv;
                rs += pv;
            }
        lacc += rs;

        // ---- pack P straight into PV B-operand regs (k-permuted) ----
        unsigned up[4];
        up[0] = pk2(st[0][0], st[0][1]);
        up[1] = pk2(st[0][2], st[0][3]);
        up[2] = pk2(st[1][0], st[1][1]);
        up[3] = pk2(st[1][2], st[1][3]);
        bf16x8 pf0;
        __builtin_memcpy(&pf0, up, 16);
        up[0] = pk2(st[2][0], st[2][1]);
        up[1] = pk2(st[2][2], st[2][3]);
        up[2] = pk2(st[3][0], st[3][1]);
        up[3] = pk2(st[3][2], st[3][3]);
        bf16x8 pf1;
        __builtin_memcpy(&pf1, up, 16);

        // ---- O^T += V^T P^T (V frags from permuted LDS; P from registers) ----
#pragma unroll
        for (int dt = 0; dt < 4; dt++) {
            bf16x8 vf0 = *(const bf16x8*)&VL[stg][((16 * dt + qm) * 8 + (quad ^ sw)) * 8];
            bf16x8 vf1 = *(const bf16x8*)&VL[stg][((16 * dt + qm) * 8 + ((4 + quad) ^ sw)) * 8];
            oacc[dt] = __builtin_amdgcn_mfma_f32_16x16x32_bf16(vf0, pf0, oacc[dt], 0, 0, 0);
            oacc[dt] = __builtin_amdgcn_mfma_f32_16x16x32_bf16(vf1, pf1, oacc[dt], 0, 0, 0);
        }

        stg = (stg == 2) ? 0 : stg + 1;
    }
    writeO(q0B);                       // flush tile B
}

// ---------- launch ----------
extern "C" void kernel_launch(void* const* d_in, const int* in_sizes, int n_in,
                              void* d_out, int out_size, void* d_ws, size_t ws_size,
                              hipStream_t stream) {
    (void)in_sizes; (void)n_in; (void)out_size; (void)ws_size;
    const float* x    = (const float*)d_in[0];
    const float* qkvo = (const float*)d_in[1];
    const float* qw   = (const float*)d_in[2];
    const float* kw   = (const float*)d_in[3];
    float* out = (float*)d_out;

    char* ws = (char*)d_ws;
    ushort* xbf = (ushort*)(ws + 0);          //  8388608 B
    ushort* wbf = (ushort*)(ws + 8388608);    //  5242880 B
    float*  qkv = (float*)(ws + 13631488);    // 25165824 B
    ushort* Qb  = (ushort*)(ws + 38797312);   //  8388608 B
    ushort* Kb  = (ushort*)(ws + 47185920);   //  2097152 B
    ushort* VT  = (ushort*)(ws + 49283072);   //  2097152 B
    ushort* Ob  = (ushort*)(ws + 51380224);   //  8388608 B

    cast_kernel<<<6656, 256, 0, stream>>>((const float4*)x, (const float4*)qkvo,
                                          (ushort4*)xbf, (ushort4*)wbf);
    gemm_bf16<<<dim3(64, 12), 256, 0, stream>>>(xbf, wbf, qkv, 4096, 1536, 1024);
    normrope_kernel<<<4096, 256, 0, stream>>>(qkv, qw, kw, Qb, Kb);
    vtrans_kernel<<<dim3(8, 32), 256, 0, stream>>>(qkv, VT);
    attn10_kernel<<<512, 256, 0, stream>>>(Qb, Kb, VT, Ob);
    gemm_bf16<<<dim3(64, 8), 256, 0, stream>>>(Ob, wbf + (size_t)1536 * 1024, out, 4096, 1024, 1024);
}